// Round 1
// baseline (30.355 us; speedup 1.0000x reference)
//
#include <hip/hip_runtime.h>
#include <math.h>

// Problem constants (match reference)
#define BB 8192
#define NN 128
// SIGMA1 = 0.01, ALPHA = BETA = 0.5

constexpr int BLOCK = 256;
constexpr int TOTAL_VEC = (BB * NN) / 4;   // 262144 float4-threads
constexpr int GRID = TOTAL_VEC / BLOCK;    // 1024 blocks

// Stage 1: per-block partial sums of
//   s1 = sum log(niw_var)          (= psi_d - log(denom))
//   s2 = sum 1/niw_var             (= denom * exp(-psi_d)); SIGMA1 applied later
//   s3 = sum d^2 / niw_var
//   s4 = sum |d| * (lmbda + nu)
__global__ __launch_bounds__(BLOCK) void niw_reduce_kernel(
    const float* __restrict__ y, const float* __restrict__ mu,
    const float* __restrict__ lmbda, const float* __restrict__ psi,
    const float* __restrict__ nu, double* __restrict__ partials)
{
    const int v = blockIdx.x * BLOCK + threadIdx.x;
    const int e = v * 4;                 // first element index
    const int b = e >> 7;                // row (N=128)
    const int j = e & 127;               // col within row (multiple of 4)

    const float4 yv  = *reinterpret_cast<const float4*>(y + e);
    const float4 muv = *reinterpret_cast<const float4*>(mu + e);
    const float4 lmv = *reinterpret_cast<const float4*>(lmbda + e);
    const float4 nuv = *reinterpret_cast<const float4*>(nu + e);

    // diagonal gather: psi[b, j+k, j+k] at stride N+1 = 129 floats
    const float* prow = psi + (size_t)b * (NN * NN) + (size_t)j * (NN + 1);
    float pd0 = prow[0];
    float pd1 = prow[129];
    float pd2 = prow[258];
    float pd3 = prow[387];

    const float yy[4] = {yv.x, yv.y, yv.z, yv.w};
    const float mm[4] = {muv.x, muv.y, muv.z, muv.w};
    const float ll[4] = {lmv.x, lmv.y, lmv.z, lmv.w};
    const float nn[4] = {nuv.x, nuv.y, nuv.z, nuv.w};
    const float pd[4] = {pd0, pd1, pd2, pd3};

    float s1 = 0.f, s2 = 0.f, s3 = 0.f, s4 = 0.f;
#pragma unroll
    for (int k = 0; k < 4; ++k) {
        float yk = yy[k];
        yk = (yk != yk) ? 0.0f : yk;     // nan_to_num
        const float d = mm[k] - yk;
        const float denom = ll[k] * (nn[k] - (float)(NN + 1));  // lmbda*(nu-n-1)
        const float logv  = pd[k] - __logf(denom);              // log(niw_var)
        const float inv_v = denom * __expf(-pd[k]);             // 1/niw_var
        s1 += logv;
        s2 += inv_v;
        s3 += d * d * inv_v;
        s4 += fabsf(d) * (ll[k] + nn[k]);
    }

    // wave (64-lane) reduction in double
    double d1 = s1, d2 = s2, d3 = s3, d4 = s4;
#pragma unroll
    for (int off = 32; off > 0; off >>= 1) {
        d1 += __shfl_down(d1, off);
        d2 += __shfl_down(d2, off);
        d3 += __shfl_down(d3, off);
        d4 += __shfl_down(d4, off);
    }

    __shared__ double sh[4][4];          // [wave][accum]
    const int wave = threadIdx.x >> 6;
    const int lane = threadIdx.x & 63;
    if (lane == 0) {
        sh[wave][0] = d1; sh[wave][1] = d2; sh[wave][2] = d3; sh[wave][3] = d4;
    }
    __syncthreads();
    if (threadIdx.x == 0) {
        double t1 = 0, t2 = 0, t3 = 0, t4 = 0;
        for (int w = 0; w < 4; ++w) {
            t1 += sh[w][0]; t2 += sh[w][1]; t3 += sh[w][2]; t4 += sh[w][3];
        }
        double* p = partials + (size_t)blockIdx.x * 4;
        p[0] = t1; p[1] = t2; p[2] = t3; p[3] = t4;
    }
}

// Stage 2: single block sums the GRID partials, emits (loss, temporal, error)
__global__ __launch_bounds__(256) void niw_finalize_kernel(
    const double* __restrict__ partials, float* __restrict__ out)
{
    double t1 = 0, t2 = 0, t3 = 0, t4 = 0;
    for (int i = threadIdx.x; i < GRID; i += 256) {
        const double* p = partials + (size_t)i * 4;
        t1 += p[0]; t2 += p[1]; t3 += p[2]; t4 += p[3];
    }
#pragma unroll
    for (int off = 32; off > 0; off >>= 1) {
        t1 += __shfl_down(t1, off);
        t2 += __shfl_down(t2, off);
        t3 += __shfl_down(t3, off);
        t4 += __shfl_down(t4, off);
    }
    __shared__ double sh[4][4];
    const int wave = threadIdx.x >> 6;
    const int lane = threadIdx.x & 63;
    if (lane == 0) {
        sh[wave][0] = t1; sh[wave][1] = t2; sh[wave][2] = t3; sh[wave][3] = t4;
    }
    __syncthreads();
    if (threadIdx.x == 0) {
        double S1 = 0, S2 = 0, S3 = 0, S4 = 0;
        for (int w = 0; w < 4; ++w) {
            S1 += sh[w][0]; S2 += sh[w][1]; S3 += sh[w][2]; S4 += sh[w][3];
        }
        const double SIGMA1 = 0.01;
        const double n = (double)NN;
        const double Bd = (double)BB;
        // temporal = 0.5 * sum_b( term1 - n + term2 + term3 )
        //   term1 over all rows = S1 - B*n*log(SIGMA1)
        //   term2 over all rows = SIGMA1 * S2
        const double temporal =
            0.5 * (S1 - Bd * n * log(SIGMA1) - Bd * n + SIGMA1 * S2 + S3);
        const double error = S4 / Bd;
        const double loss = 0.5 * temporal + 0.5 * error;
        out[0] = (float)loss;
        out[1] = (float)temporal;
        out[2] = (float)error;
    }
}

extern "C" void kernel_launch(void* const* d_in, const int* in_sizes, int n_in,
                              void* d_out, int out_size, void* d_ws, size_t ws_size,
                              hipStream_t stream) {
    const float* y     = (const float*)d_in[0];
    const float* mu    = (const float*)d_in[1];
    const float* lmbda = (const float*)d_in[2];
    const float* psi   = (const float*)d_in[3];
    const float* nu    = (const float*)d_in[4];
    float* out = (float*)d_out;
    double* partials = (double*)d_ws;    // needs GRID*4*8 = 32 KiB

    niw_reduce_kernel<<<GRID, BLOCK, 0, stream>>>(y, mu, lmbda, psi, nu, partials);
    niw_finalize_kernel<<<1, 256, 0, stream>>>(partials, out);
}